// Round 1
// baseline (1402.219 us; speedup 1.0000x reference)
//
#include <hip/hip_runtime.h>
#include <stdint.h>

#define B_ROWS 64
#define D_DIM  2048
#define V_DIM  128000
#define N_TILE 128
#define NBLK   (V_DIM / N_TILE)   /* 1000 */
#define KCH    (D_DIM / 32)       /* 64   */

typedef float  f32x4  __attribute__((ext_vector_type(4)));
typedef __bf16 bf16x8 __attribute__((ext_vector_type(8)));

/* ---------------- phase 0: gather rows + fp32 -> (hi,lo) bf16 split,
   stored pre-swizzled in MFMA A-fragment order:
   element (m,k): c=k>>5, t=m>>4, quad=(k>>3)&3, j=k&7, lane=quad*16+(m&15)
   offset = ((c*4+t)*64 + lane)*8 + j                                    */
__global__ void prep_A(const float* __restrict__ hs, const int* __restrict__ idx,
                       __bf16* __restrict__ Ah, __bf16* __restrict__ Al)
{
    const int b   = blockIdx.x;    // 0..63
    const int tid = threadIdx.x;   // 0..255, covers k = tid*8 .. +7
    const int row = idx[b];
    const int k0  = tid * 8;
    const float* src = hs + (long)row * D_DIM + k0;
    const int c    = tid >> 2;
    const int quad = tid & 3;
    const int t    = b >> 4;
    const int lane = quad * 16 + (b & 15);
    const long off = ((long)(c * 4 + t) * 64 + lane) * 8;
    bf16x8 vh, vl;
#pragma unroll
    for (int j = 0; j < 8; j++) {
        float x = src[j];
        __bf16 h = (__bf16)x;              // RNE
        vh[j] = h;
        vl[j] = (__bf16)(x - (float)h);    // exact residual, then RNE
    }
    *(bf16x8*)(Ah + off) = vh;
    *(bf16x8*)(Al + off) = vl;
}

/* ---------------- main: 64 x V split-bf16 GEMM + fused tile reductions ----
   grid = 1000 blocks of 256 (4 waves). Wave w owns weight rows
   v0+w*32 .. +31. Per 32-wide K chunk: wave DMAs its own 32x32 fp32
   sub-tile into its private LDS region (double buffered, XOR-swizzled),
   no __syncthreads in the K loop.                                          */
__global__ void gemm_sample(const float* __restrict__ W,
                            const __bf16* __restrict__ Ah,
                            const __bf16* __restrict__ Al,
                            const float* __restrict__ temp,
                            const float* __restrict__ gum,
                            f32x4* __restrict__ partA,
                            float* __restrict__ partB)
{
    __shared__ float smem[8256];          // 32KB staging (4 waves x 2 x 4KB) / 64x129 logits
    const int tid  = threadIdx.x;
    const int wid  = tid >> 6;
    const int lane = tid & 63;
    const int v0   = blockIdx.x * N_TILE;

    float* wreg = smem + wid * 2048;      // this wave's 2 staging buffers

    const int srow = lane >> 3;           // staging row within 8-row group
    const int spb  = lane & 7;            // 16B block within row

    auto stage = [&](int c, int buf) {
        float* lb = wreg + buf * 1024;
#pragma unroll
        for (int cc = 0; cc < 4; cc++) {
            int rl   = cc * 8 + srow;                 // 0..31 local weight row
            int kblk = spb ^ (rl & 7);                // XOR swizzle (16B units)
            const float* g = W + (long)(v0 + wid * 32 + rl) * D_DIM + c * 32 + kblk * 4;
            __builtin_amdgcn_global_load_lds(
                (const __attribute__((address_space(1))) void*)g,
                (__attribute__((address_space(3))) void*)(lb + cc * 256),
                16, 0, 0);
        }
    };

    f32x4 acc[4][2];
#pragma unroll
    for (int t = 0; t < 4; t++)
#pragma unroll
        for (int u = 0; u < 2; u++)
            acc[t][u] = (f32x4){0.f, 0.f, 0.f, 0.f};

    const int r0 = lane & 15;
    const int q  = lane >> 4;
    const __bf16* aph = Ah + lane * 8;
    const __bf16* apl = Al + lane * 8;

    stage(0, 0);
    for (int c = 0; c < KCH; c++) {
        const int buf = c & 1;
        if (c + 1 < KCH) {
            stage(c + 1, buf ^ 1);
            // drain everything older than the 4 just-issued DMAs:
            // current chunk's LDS data is guaranteed resident, prefetch stays in flight
            asm volatile("s_waitcnt vmcnt(4)" ::: "memory");
        } else {
            asm volatile("s_waitcnt vmcnt(0)" ::: "memory");
        }
        bf16x8 ah[4], al[4];
#pragma unroll
        for (int t = 0; t < 4; t++) {       // coalesced 1KB fragment loads (L1/L2-hot)
            ah[t] = *(const bf16x8*)(aph + (long)(c * 4 + t) * 512);
            al[t] = *(const bf16x8*)(apl + (long)(c * 4 + t) * 512);
        }
        const float* lb = wreg + buf * 1024;
#pragma unroll
        for (int u = 0; u < 2; u++) {
            const int r = u * 16 + r0;
            const float* rp = lb + r * 32;
            f32x4 w0 = *(const f32x4*)(rp + (((2 * q)     ^ (r & 7)) * 4));
            f32x4 w1 = *(const f32x4*)(rp + (((2 * q + 1) ^ (r & 7)) * 4));
            bf16x8 wh, wl;
#pragma unroll
            for (int j = 0; j < 4; j++) {
                float x = w0[j];
                __bf16 h = (__bf16)x;
                wh[j] = h; wl[j] = (__bf16)(x - (float)h);
            }
#pragma unroll
            for (int j = 0; j < 4; j++) {
                float x = w1[j];
                __bf16 h = (__bf16)x;
                wh[4 + j] = h; wl[4 + j] = (__bf16)(x - (float)h);
            }
#pragma unroll
            for (int t = 0; t < 4; t++) {   // 3-term split: hh + lh + hl
                acc[t][u] = __builtin_amdgcn_mfma_f32_16x16x32_bf16(ah[t], wh, acc[t][u], 0, 0, 0);
                acc[t][u] = __builtin_amdgcn_mfma_f32_16x16x32_bf16(al[t], wh, acc[t][u], 0, 0, 0);
                acc[t][u] = __builtin_amdgcn_mfma_f32_16x16x32_bf16(ah[t], wl, acc[t][u], 0, 0, 0);
            }
        }
    }

    __syncthreads();                       // staging LDS -> logits LDS aliasing
    // C/D layout: col = lane&15, row = quad*4 + reg   (raw, un-scaled logits)
#pragma unroll
    for (int t = 0; t < 4; t++)
#pragma unroll
        for (int u = 0; u < 2; u++)
#pragma unroll
            for (int r = 0; r < 4; r++) {
                int m = t * 16 + q * 4 + r;
                int n = wid * 32 + u * 16 + r0;
                smem[m * 129 + n] = acc[t][u][r];
            }
    __syncthreads();

    // tile reductions: 4 threads per logits row, stride-4 columns
    const int brow = tid >> 2;
    const int qq   = tid & 3;
    const float invT = 1.0f / temp[brow];
    const float* lrow = smem + brow * 129;
    const float* grow = gum + (long)brow * V_DIM + v0;

    float gmax = -INFINITY; int gidx = 0;
    float smax = -INFINITY; int sidx = 0;
#pragma unroll 8
    for (int i = 0; i < 32; i++) {
        int col = qq + 4 * i;
        float L = lrow[col];
        if (L > gmax) { gmax = L; gidx = col; }
        float s = L * invT + grow[col];
        if (s > smax) { smax = s; sidx = col; }
    }
#pragma unroll
    for (int d = 1; d < 4; d <<= 1) {      // combine the 4 threads of this row
        float og = __shfl_xor(gmax, d); int oi = __shfl_xor(gidx, d);
        if (og > gmax || (og == gmax && oi < gidx)) { gmax = og; gidx = oi; }
        float os = __shfl_xor(smax, d); int si = __shfl_xor(sidx, d);
        if (os > smax || (os == smax && si < sidx)) { smax = os; sidx = si; }
    }
    float lsum = 0.f;                       // tile LSE relative to gmax*invT
#pragma unroll 8
    for (int i = 0; i < 32; i++) {
        int col = qq + 4 * i;
        lsum += __expf((lrow[col] - gmax) * invT);
    }
    lsum += __shfl_xor(lsum, 1);
    lsum += __shfl_xor(lsum, 2);
    if (qq == 0) {
        f32x4 p;
        p[0] = gmax; p[1] = __int_as_float(v0 + gidx);
        p[2] = smax; p[3] = __int_as_float(v0 + sidx);
        partA[(long)brow * NBLK + blockIdx.x] = p;
        partB[(long)brow * NBLK + blockIdx.x] = lsum;
    }
}

/* ---------------- finalize: combine 1000 partials per row ---------------- */
__global__ void finalize(const f32x4* __restrict__ partA, const float* __restrict__ partB,
                         const float* __restrict__ temp, const int* __restrict__ gmask,
                         const float* __restrict__ gum, float* __restrict__ out)
{
    const int b = blockIdx.x;
    const int tid = threadIdx.x;
    const float invT = 1.0f / temp[b];
    float mg = -INFINITY; int ig = 0;
    float ms = -INFINITY; int is_ = 0;
    float mx = -INFINITY; float sm = 0.f;
    for (int i = tid; i < NBLK; i += 256) {
        f32x4 p = partA[(long)b * NBLK + i];
        float ls = partB[(long)b * NBLK + i];
        int vi = __float_as_int(p[1]);
        if (p[0] > mg || (p[0] == mg && vi < ig)) { mg = p[0]; ig = vi; }
        int si = __float_as_int(p[3]);
        if (p[2] > ms || (p[2] == ms && si < is_)) { ms = p[2]; is_ = si; }
        float m2 = p[0] * invT;                    // tile's scaled max
        if (m2 > mx) { sm = sm * __expf(mx - m2) + ls; mx = m2; }
        else         { sm = sm + ls * __expf(m2 - mx); }
    }
#pragma unroll
    for (int d = 1; d < 64; d <<= 1) {
        float og = __shfl_xor(mg, d); int oi = __shfl_xor(ig, d);
        if (og > mg || (og == mg && oi < ig)) { mg = og; ig = oi; }
        float os = __shfl_xor(ms, d); int si = __shfl_xor(is_, d);
        if (os > ms || (os == ms && si < is_)) { ms = os; is_ = si; }
        float omx = __shfl_xor(mx, d); float osm = __shfl_xor(sm, d);
        if (omx > mx) { sm = sm * __expf(mx - omx) + osm; mx = omx; }
        else          { sm = sm + osm * __expf(omx - mx); }
    }
    __shared__ float red[4][8];
    const int w = tid >> 6;
    if ((tid & 63) == 0) {
        red[w][0] = mg; red[w][1] = __int_as_float(ig);
        red[w][2] = ms; red[w][3] = __int_as_float(is_);
        red[w][4] = mx; red[w][5] = sm;
    }
    __syncthreads();
    if (tid == 0) {
#pragma unroll
        for (int w2 = 1; w2 < 4; w2++) {
            float og = red[w2][0]; int oi = __float_as_int(red[w2][1]);
            if (og > mg || (og == mg && oi < ig)) { mg = og; ig = oi; }
            float os = red[w2][2]; int si = __float_as_int(red[w2][3]);
            if (os > ms || (os == ms && si < is_)) { ms = os; is_ = si; }
            float omx = red[w2][4], osm = red[w2][5];
            if (omx > mx) { sm = sm * __expf(mx - omx) + osm; mx = omx; }
            else          { sm = sm + osm * __expf(omx - mx); }
        }
        float logZ = mx + logf(sm);
        int id; float lp;
        if (gmask[b] != 0) { id = ig; lp = mg * invT - logZ; }
        else { id = is_; lp = (ms - gum[(long)b * V_DIM + is_]) - logZ; }
        out[b] = (float)id;          // ids < 2^24: exact in fp32
        out[B_ROWS + b] = lp;
    }
}

extern "C" void kernel_launch(void* const* d_in, const int* in_sizes, int n_in,
                              void* d_out, int out_size, void* d_ws, size_t ws_size,
                              hipStream_t stream)
{
    (void)in_sizes; (void)n_in; (void)out_size; (void)ws_size;
    const float* hs   = (const float*)d_in[0];
    const float* W    = (const float*)d_in[1];
    const float* temp = (const float*)d_in[2];
    const float* gum  = (const float*)d_in[3];
    const int*   idx  = (const int*)d_in[4];
    const int*   mask = (const int*)d_in[5];
    float* out = (float*)d_out;

    char* ws = (char*)d_ws;
    __bf16* Ah   = (__bf16*)ws;                         // 256 KB
    __bf16* Al   = (__bf16*)(ws + 262144);              // 256 KB
    f32x4*  pA   = (f32x4*)(ws + 524288);               // 64*1000*16 = 1,024,000 B
    float*  pB   = (float*)(ws + 524288 + 1024000);     // 64*1000*4  =   256,000 B

    prep_A     <<<B_ROWS, 256, 0, stream>>>(hs, idx, Ah, Al);
    gemm_sample<<<NBLK,   256, 0, stream>>>(W, Ah, Al, temp, gum, pA, pB);
    finalize   <<<B_ROWS, 256, 0, stream>>>(pA, pB, temp, mask, gum, out);
}